// Round 1
// baseline (697.630 us; speedup 1.0000x reference)
//
#include <hip/hip_runtime.h>
#include <hip/hip_bf16.h>
#include <stdint.h>

// Problem dims (fixed by reference)
#define T_LEN 128
#define B_SZ  256
#define D_IN  1024
#define H_DIM 1024
#define NQ    8
#define VOCAB 32000
#define TAGS  1024

typedef __attribute__((ext_vector_type(8))) short short8;   // 8 bf16 (4 VGPRs)
typedef __attribute__((ext_vector_type(4))) float f32x4;

// ---------- helpers ----------
__device__ __forceinline__ unsigned short f2bf_bits(float x) {
    __hip_bfloat16 h = __float2bfloat16(x);
    unsigned short u; __builtin_memcpy(&u, &h, 2); return u;
}
__device__ __forceinline__ uint32_t pack_bf2(float a, float b) {
    return (uint32_t)f2bf_bits(a) | ((uint32_t)f2bf_bits(b) << 16);
}
__device__ __forceinline__ float2 unpack_bf2(uint32_t u) {
    float2 r;
    r.x = __uint_as_float(u << 16);
    r.y = __uint_as_float(u & 0xffff0000u);
    return r;
}
__device__ __forceinline__ float sigmoid_f(float x) {
    return 1.f / (1.f + __expf(-x));
}
__device__ __forceinline__ float tanh_f(float x) {
    // 1 - 2/(e^{2x}+1); saturates correctly at +/-1 (inf-safe)
    return 1.f - 2.f / (__expf(2.f * x) + 1.f);
}
__device__ __forceinline__ void gload_lds16(void* lds_base, const void* gptr) {
    __builtin_amdgcn_global_load_lds(
        (__attribute__((address_space(1))) const void*)gptr,
        (__attribute__((address_space(3))) void*)lds_base,
        16, 0, 0);
}

// ---------- K0: W_tag (K x N fp32) -> WtT (N x K bf16) ----------
__global__ __launch_bounds__(256) void k_wt_transpose(const float* __restrict__ W,
                                                      __hip_bfloat16* __restrict__ WtT) {
    __shared__ float tile[32][33];
    const int kb = blockIdx.x * 32, nb = blockIdx.y * 32;
    const int r = threadIdx.x >> 5, c = threadIdx.x & 31;
#pragma unroll
    for (int i = 0; i < 4; ++i)
        tile[r + 8 * i][c] = W[(size_t)(kb + r + 8 * i) * TAGS + nb + c];
    __syncthreads();
#pragma unroll
    for (int i = 0; i < 4; ++i)
        WtT[(size_t)(nb + r + 8 * i) * H_DIM + kb + c] = __float2bfloat16(tile[c][r + 8 * i]);
}

// ---------- K2: recurrent QLSTM. one block per batch element ----------
__global__ __launch_bounds__(1024) void k_qlstm(
    const int* __restrict__ sent, const float* __restrict__ emb,
    const float* __restrict__ Wg, const float* __restrict__ bg,
    const float* __restrict__ theta, const float* __restrict__ Wp,
    const float* __restrict__ bp, __hip_bfloat16* __restrict__ hb)
{
    __shared__ float comb[2048];      // [0..1023]=x_t, [1024..2047]=h_{t-1}
    __shared__ float red[32 * 17];    // partials: [out][wave], stride 17 (bank-safe)
    __shared__ float qs[32];          // cos() outputs

    const int tid  = threadIdx.x;
    const int b    = blockIdx.x;
    const int o    = tid & 31;        // output index (g*8+q)
    const int s    = tid >> 5;        // k-slice 0..31 (64 elems each)
    const int g    = o >> 3, q = o & 7;
    const int lane = tid & 63, wv = tid >> 6;

    // phase-1 weights: Wg[g][c][q] for c in [s*64, s*64+64), bf16-packed pairs
    uint32_t wg2[32];
#pragma unroll
    for (int j = 0; j < 32; ++j) {
        const int c0 = s * 64 + 2 * j;
        float a = Wg[((size_t)g * 2048 + c0) * 8 + q];
        float bb = Wg[((size_t)g * 2048 + c0 + 1) * 8 + q];
        wg2[j] = pack_bf2(a, bb);
    }
    // phase-2 weights: Wp[g][qq][h=tid], packed pairs over qq
    uint32_t wp2[16];
#pragma unroll
    for (int j = 0; j < 16; ++j) {
        const int gg = j >> 2, jj = j & 3;
        float a = Wp[(size_t)(gg * 8 + 2 * jj) * H_DIM + tid];
        float bb = Wp[(size_t)(gg * 8 + 2 * jj + 1) * H_DIM + tid];
        wp2[j] = pack_bf2(a, bb);
    }
    float bpv[4];
#pragma unroll
    for (int gg = 0; gg < 4; ++gg) bpv[gg] = bp[gg * H_DIM + tid];
    const float bgt = (tid < 32) ? (bg[tid] + theta[tid]) : 0.f;

    float cx = 0.f;
    comb[1024 + tid] = 0.f;                      // h_{-1} = 0
    {
        const int w0 = sent[b];                  // sentence[0][b]
        comb[tid] = emb[(size_t)w0 * D_IN + tid];
    }
    __syncthreads();

    for (int t = 0; t < T_LEN; ++t) {
        // prefetch next x (independent of everything in this step)
        const int tn = (t + 1 < T_LEN) ? (t + 1) : (T_LEN - 1);
        const int wn = sent[tn * B_SZ + b];
        const float xnext = emb[(size_t)wn * D_IN + tid];

        // ---- phase 1: raw[o] partial over k-slice s ----
        float acc = 0.f;
        const float4* c4 = (const float4*)comb;
#pragma unroll
        for (int i = 0; i < 16; ++i) {
            float4 v = c4[s * 16 + i];
            float2 wa = unpack_bf2(wg2[2 * i]);
            float2 wb = unpack_bf2(wg2[2 * i + 1]);
            acc = fmaf(wa.x, v.x, acc);
            acc = fmaf(wa.y, v.y, acc);
            acc = fmaf(wb.x, v.z, acc);
            acc = fmaf(wb.y, v.w, acc);
        }
        acc += __shfl_xor(acc, 32, 64);          // fold the two half-wave slices
        if (lane < 32) red[lane * 17 + wv] = acc;
        __syncthreads();                          // B1

        // ---- cross-wave reduce + quantum layer (32 lanes) ----
        if (tid < 32) {
            float r = bgt;
#pragma unroll
            for (int w = 0; w < 16; ++w) r += red[tid * 17 + w];
            qs[tid] = __cosf(r);                  // <Z> = cos(raw + theta)
        }
        comb[tid] = xnext;                        // stage x_{t+1} (phase1 reads done)
        __syncthreads();                          // B2

        // ---- phase 2: projection + gates, one h per thread ----
        const float4* q4 = (const float4*)qs;
        float pj[4];
#pragma unroll
        for (int gg = 0; gg < 4; ++gg) {
            float4 u = q4[2 * gg], v = q4[2 * gg + 1];
            float2 w0 = unpack_bf2(wp2[gg * 4 + 0]);
            float2 w1 = unpack_bf2(wp2[gg * 4 + 1]);
            float2 w2 = unpack_bf2(wp2[gg * 4 + 2]);
            float2 w3 = unpack_bf2(wp2[gg * 4 + 3]);
            pj[gg] = bpv[gg]
                   + u.x * w0.x + u.y * w0.y + u.z * w1.x + u.w * w1.y
                   + v.x * w2.x + v.y * w2.y + v.z * w3.x + v.w * w3.y;
        }
        const float f_ = sigmoid_f(pj[0]);
        const float i_ = sigmoid_f(pj[1]);
        const float g_ = tanh_f(pj[2]);
        const float o_ = sigmoid_f(pj[3]);
        cx = f_ * cx + i_ * g_;
        const float hv = o_ * tanh_f(cx);
        comb[1024 + tid] = hv;
        hb[((size_t)t * B_SZ + b) * H_DIM + tid] = __float2bfloat16(hv);
        __syncthreads();                          // B3
    }
}

// ---------- K3: tag GEMM  C(32768x1024 f32) = Hb(bf16) x W_tag(bf16) ----------
// 128x128 block tile, 4 waves in 2x2, 64x64 per wave (4x4 MFMA frags)
__global__ __launch_bounds__(256) void k_tag_gemm(const __hip_bfloat16* __restrict__ Hb,
                                                  const __hip_bfloat16* __restrict__ WtT,
                                                  float* __restrict__ out)
{
    __shared__ short As[128 * 32];   // [row][k] bf16, unpadded (global_load_lds layout)
    __shared__ short Bs[128 * 32];   // [n][k]   bf16
    const int m0 = blockIdx.x * 128, n0 = blockIdx.y * 128;
    const int tid = threadIdx.x, lane = tid & 63, wid = tid >> 6;
    const int wm = (wid & 1) * 64, wn = (wid >> 1) * 64;
    const int mrow = lane & 15, quad = lane >> 4;

    const short* Hs = (const short*)Hb;
    const short* Ws = (const short*)WtT;

    f32x4 acc[4][4];
#pragma unroll
    for (int mi = 0; mi < 4; ++mi)
#pragma unroll
        for (int ni = 0; ni < 4; ++ni)
            acc[mi][ni] = (f32x4){0.f, 0.f, 0.f, 0.f};

    for (int kt = 0; kt < 32; ++kt) {
        const int k0 = kt * 32;
        __syncthreads();   // protect LDS from previous iteration's readers
        // stage A (8 KB) + B (8 KB): each wave owns 1KB chunks; lane scatter = row-major
#pragma unroll
        for (int ch = 0; ch < 2; ++ch) {
            const int chunk = wid + ch * 4;                 // 0..7
            const int row = chunk * 16 + (lane >> 2);
            const int kc = (lane & 3) * 8;
            gload_lds16(&As[chunk * 512], &Hs[(size_t)(m0 + row) * H_DIM + k0 + kc]);
            gload_lds16(&Bs[chunk * 512], &Ws[(size_t)(n0 + row) * H_DIM + k0 + kc]);
        }
        __syncthreads();   // compiler drains vmcnt before barrier

        short8 afr[4], bfr[4];
#pragma unroll
        for (int mi = 0; mi < 4; ++mi)
            afr[mi] = *(const short8*)&As[(wm + mi * 16 + mrow) * 32 + quad * 8];
#pragma unroll
        for (int ni = 0; ni < 4; ++ni)
            bfr[ni] = *(const short8*)&Bs[(wn + ni * 16 + mrow) * 32 + quad * 8];
#pragma unroll
        for (int mi = 0; mi < 4; ++mi)
#pragma unroll
            for (int ni = 0; ni < 4; ++ni)
                acc[mi][ni] = __builtin_amdgcn_mfma_f32_16x16x32_bf16(
                    afr[mi], bfr[ni], acc[mi][ni], 0, 0, 0);
    }

    // epilogue: D row = quad*4 + r, col = lane&15  (no bias: b_tag cancels in log_softmax)
#pragma unroll
    for (int mi = 0; mi < 4; ++mi)
#pragma unroll
        for (int ni = 0; ni < 4; ++ni)
#pragma unroll
            for (int r = 0; r < 4; ++r) {
                const int grow = m0 + wm + mi * 16 + quad * 4 + r;
                const int gcol = n0 + wn + ni * 16 + mrow;
                out[(size_t)grow * TAGS + gcol] = acc[mi][ni][r];
            }
}

// ---------- K4: log_softmax over batch axis (axis=1 of (T,B,TAGS)), in-place ----------
__global__ __launch_bounds__(256) void k_logsoftmax(float* __restrict__ out) {
    const int t = blockIdx.x;
    const int n = blockIdx.y * 256 + threadIdx.x;
    float* base = out + (size_t)t * B_SZ * TAGS + n;
    float m = -1e30f;
    for (int b = 0; b < B_SZ; ++b) m = fmaxf(m, base[(size_t)b * TAGS]);
    float s = 0.f;
    for (int b = 0; b < B_SZ; ++b) s += __expf(base[(size_t)b * TAGS] - m);
    const float lse = m + __logf(s);
    for (int b = 0; b < B_SZ; ++b) base[(size_t)b * TAGS] -= lse;
}

extern "C" void kernel_launch(void* const* d_in, const int* in_sizes, int n_in,
                              void* d_out, int out_size, void* d_ws, size_t ws_size,
                              hipStream_t stream) {
    (void)in_sizes; (void)n_in; (void)out_size; (void)ws_size;
    const int*   sent  = (const int*)d_in[0];
    const float* emb   = (const float*)d_in[1];
    const float* Wg    = (const float*)d_in[2];
    const float* bg    = (const float*)d_in[3];
    const float* theta = (const float*)d_in[4];
    const float* Wp    = (const float*)d_in[5];
    const float* bp    = (const float*)d_in[6];
    const float* Wt    = (const float*)d_in[7];
    // d_in[8] = b_tag: constant along the softmax (batch) axis -> cancels exactly.
    float* out = (float*)d_out;

    __hip_bfloat16* hb  = (__hip_bfloat16*)d_ws;                                   // 64 MB: lstm_out bf16
    __hip_bfloat16* WtT = (__hip_bfloat16*)((char*)d_ws + (size_t)64 * 1024 * 1024); // 2 MB: W_tag^T bf16

    k_wt_transpose<<<dim3(32, 32), 256, 0, stream>>>(Wt, WtT);
    k_qlstm<<<dim3(B_SZ), 1024, 0, stream>>>(sent, emb, Wg, bg, theta, Wp, bp, hb);
    k_tag_gemm<<<dim3(256, 8), 256, 0, stream>>>(hb, WtT, out);
    k_logsoftmax<<<dim3(T_LEN, 4), 256, 0, stream>>>(out);
}